// Round 1
// baseline (191.412 us; speedup 1.0000x reference)
//
#include <hip/hip_runtime.h>
#include <math.h>

#define NPTS 512
#define KNN  20

// Lexicographic (dist, idx) argmin across the 64-lane wave; all lanes converge.
__device__ __forceinline__ void argmin64(float& bd, int& bi) {
    #pragma unroll
    for (int off = 32; off >= 1; off >>= 1) {
        float od = __shfl_xor(bd, off, 64);
        int   oi = __shfl_xor(bi, off, 64);
        if (od < bd || (od == bd && oi < bi)) { bd = od; bi = oi; }
    }
}

// ---------------------------------------------------------------------------
// Stage 1: per-row KNN on raw 16-dim points, wFM over 20 neighbors,
// write R[b,n,d] (the 16-dim Frechet mean; fm1 = outer(R, w_mix1) implicitly)
// and sqr[b,n] = ||R||^2 (fma-chain in d-order so stage-2 diagonal is exact 0).
// ---------------------------------------------------------------------------
__global__ __launch_bounds__(64)
void stage1_kernel(const float* __restrict__ x,      // [B,512,16]
                   const float* __restrict__ w_fm1,  // [20]
                   float* __restrict__ R,            // [B,512,16]
                   float* __restrict__ sqr)          // [B,512]
{
    const int row = blockIdx.x;          // b*512 + n
    const int b   = row >> 9;
    const int t   = threadIdx.x;         // 0..63 (one wave)
    const float* xb = x + (size_t)b * NPTS * 16;
    const float* xn = x + (size_t)row * 16;

    float own[16];
    #pragma unroll
    for (int d = 0; d < 16; ++d) own[d] = xn[d];
    float sqn = 0.f;
    #pragma unroll
    for (int d = 0; d < 16; ++d) sqn = fmaf(own[d], own[d], sqn);

    // Each lane scans 8 candidates (m = j*64 + t, increasing m => index tiebreak),
    // keeping all 8 sorted ascending by (dist, idx).
    float cd[8]; int ci[8];
    #pragma unroll
    for (int j = 0; j < 8; ++j) { cd[j] = __builtin_inff(); ci[j] = 0x7fffffff; }
    #pragma unroll
    for (int j = 0; j < 8; ++j) {
        const int m = j * 64 + t;
        const float* xm = xb + m * 16;
        float dot = 0.f, sqm = 0.f;
        #pragma unroll
        for (int d = 0; d < 16; ++d) {
            const float v = xm[d];
            dot = fmaf(own[d], v, dot);
            sqm = fmaf(v, v, sqm);
        }
        float vd = sqn + sqm - 2.f * dot;   // == 0 exactly when m == n
        int   vi = m;
        #pragma unroll
        for (int i = 0; i < 8; ++i) {       // branchless sorted insert
            const bool sw = vd < cd[i];
            const float td = sw ? cd[i] : vd; const int ti = sw ? ci[i] : vi;
            cd[i] = sw ? vd : cd[i];          ci[i] = sw ? vi : ci[i];
            vd = td; vi = ti;
        }
    }

    __shared__ float sd[64][8];
    __shared__ int   si[64][8];
    #pragma unroll
    for (int j = 0; j < 8; ++j) { sd[t][j] = cd[j]; si[t][j] = ci[j]; }
    __syncthreads();

    // 20-round merge: extract global (dist, idx)-min; winner lane advances head.
    int h = 0;
    int nbr[KNN];
    #pragma unroll
    for (int r = 0; r < KNN; ++r) {
        float myd = (h < 8) ? sd[t][h] : __builtin_inff();
        int   myi = (h < 8) ? si[t][h] : 0x7fffffff;
        float bd = myd; int bi = myi;
        argmin64(bd, bi);
        if (myi == bi) ++h;       // indices unique -> exactly one lane advances
        nbr[r] = bi;              // every lane keeps the full ordered list
    }

    // softmax over w_fm1 (k axis), computed redundantly per lane (tiny)
    float w[KNN];
    float wmax = -__builtin_inff();
    #pragma unroll
    for (int k = 0; k < KNN; ++k) { w[k] = w_fm1[k]; wmax = fmaxf(wmax, w[k]); }
    float wsum = 0.f;
    #pragma unroll
    for (int k = 0; k < KNN; ++k) { w[k] = __expf(w[k] - wmax); wsum += w[k]; }
    const float winv = 1.f / wsum;

    __shared__ float rbuf[16];
    if (t < 16) {
        float acc = 0.f;
        #pragma unroll
        for (int k = 0; k < KNN; ++k)
            acc = fmaf(w[k] * winv, xb[nbr[k] * 16 + t], acc);
        R[(size_t)row * 16 + t] = acc;
        rbuf[t] = acc;
    }
    __syncthreads();
    if (t == 0) {
        float s = 0.f;
        #pragma unroll
        for (int d = 0; d < 16; ++d) s = fmaf(rbuf[d], rbuf[d], s);  // same chain as stage-2 dot
        sqr[row] = s;
    }
}

// ---------------------------------------------------------------------------
// Stage 2: KNN on R (order-equivalent to 480-dim distances since
// fm1 = outer(R, w_mix1)), then fused wFM2 + mix2 + manifold distance + pool.
// ---------------------------------------------------------------------------
__global__ __launch_bounds__(64)
void stage2_kernel(const float* __restrict__ R,       // [B,512,16]
                   const float* __restrict__ sqr,     // [B,512]
                   const float* __restrict__ w_fm2,   // [30,20]
                   const float* __restrict__ w_mix1,  // [30]
                   const float* __restrict__ w_mix2,  // [30,50]
                   const float* __restrict__ m_last,  // [16,50]
                   float* __restrict__ pooled)        // [B,512]
{
    const int row = blockIdx.x;
    const int b   = row >> 9;
    const int t   = threadIdx.x;
    const float* Rb = R + (size_t)b * NPTS * 16;
    const float* sb = sqr + b * NPTS;
    const float* rn = R + (size_t)row * 16;

    float own[16];
    #pragma unroll
    for (int d = 0; d < 16; ++d) own[d] = rn[d];
    const float sqn = sb[row & (NPTS - 1)];

    float cd[8]; int ci[8];
    #pragma unroll
    for (int j = 0; j < 8; ++j) { cd[j] = __builtin_inff(); ci[j] = 0x7fffffff; }
    #pragma unroll
    for (int j = 0; j < 8; ++j) {
        const int m = j * 64 + t;
        const float* rm = Rb + m * 16;
        float dot = 0.f;
        #pragma unroll
        for (int d = 0; d < 16; ++d) dot = fmaf(own[d], rm[d], dot);  // matches sqr chain -> diag == 0
        float vd = sqn + sb[m] - 2.f * dot;
        int   vi = m;
        #pragma unroll
        for (int i = 0; i < 8; ++i) {
            const bool sw = vd < cd[i];
            const float td = sw ? cd[i] : vd; const int ti = sw ? ci[i] : vi;
            cd[i] = sw ? vd : cd[i];          ci[i] = sw ? vi : ci[i];
            vd = td; vi = ti;
        }
    }

    __shared__ float sd[64][8];
    __shared__ int   si[64][8];
    #pragma unroll
    for (int j = 0; j < 8; ++j) { sd[t][j] = cd[j]; si[t][j] = ci[j]; }
    __syncthreads();

    int h = 0;
    int nbr[KNN];
    #pragma unroll
    for (int r = 0; r < KNN; ++r) {
        float myd = (h < 8) ? sd[t][h] : __builtin_inff();
        int   myi = (h < 8) ? si[t][h] : 0x7fffffff;
        float bd = myd; int bi = myi;
        argmin64(bd, bi);
        if (myi == bi) ++h;
        nbr[r] = bi;
    }

    __shared__ float wc2[30][KNN + 1];   // +1 pad: stride 21 coprime to 32 banks
    __shared__ float NR[KNN][16];
    __shared__ float Gs[480];            // fm2_raw laid out [d][c] = d*30+c

    if (t < 30) {                        // softmax rows of w_fm2 over k
        float wr[KNN]; float mx = -__builtin_inff();
        #pragma unroll
        for (int k = 0; k < KNN; ++k) { wr[k] = w_fm2[t * KNN + k]; mx = fmaxf(mx, wr[k]); }
        float s = 0.f;
        #pragma unroll
        for (int k = 0; k < KNN; ++k) { wr[k] = __expf(wr[k] - mx); s += wr[k]; }
        const float inv = 1.f / s;
        #pragma unroll
        for (int k = 0; k < KNN; ++k) wc2[t][k] = wr[k] * inv;
    }
    if (t < 16) {                        // gather 20 neighbor R-rows
        #pragma unroll
        for (int k = 0; k < KNN; ++k) NR[k][t] = Rb[nbr[k] * 16 + t];
    }
    __syncthreads();

    // fm2_raw[d][c] = w_mix1[c] * sum_k wc2[c][k] * NR[k][d]
    for (int f = t; f < 480; f += 64) {
        const int d = f / 30;
        const int c = f - d * 30;
        float acc = 0.f;
        #pragma unroll
        for (int k = 0; k < KNN; ++k) acc = fmaf(wc2[c][k], NR[k][d], acc);
        Gs[f] = w_mix1[c] * acc;
    }
    __syncthreads();

    // Tail: lane t<50 handles output channel f=t:
    //   dist50[f] = sqrt( sum_d ( sum_c Gs[d][c]*w_mix2[c][f] - m_last[d][f] )^2 + 1e-8 )
    float dist50 = 0.f;
    if (t < 50) {
        float wcol[30];
        #pragma unroll
        for (int c = 0; c < 30; ++c) wcol[c] = w_mix2[c * 50 + t];
        float acc = 0.f;
        #pragma unroll
        for (int d = 0; d < 16; ++d) {
            float v = 0.f;
            #pragma unroll
            for (int c = 0; c < 30; ++c) v = fmaf(Gs[d * 30 + c], wcol[c], v);
            v -= m_last[d * 50 + t];
            acc = fmaf(v, v, acc);
        }
        dist50 = sqrtf(acc + 1e-8f);
    }
    float s = dist50;
    #pragma unroll
    for (int off = 32; off >= 1; off >>= 1) s += __shfl_xor(s, off, 64);
    if (t == 0) pooled[row] = s / 50.0f;
}

// ---------------------------------------------------------------------------
// Classifier: out[b,j] = sum_n pooled[b,n] * w_cls[n,j] + b_cls[j]
// ---------------------------------------------------------------------------
__global__ __launch_bounds__(64)
void classify_kernel(const float* __restrict__ pooled,  // [B,512]
                     const float* __restrict__ w_cls,   // [512,40]
                     const float* __restrict__ b_cls,   // [40]
                     float* __restrict__ out)           // [B,40]
{
    const int b = blockIdx.x;
    const int t = threadIdx.x;
    if (t < 40) {
        float acc = b_cls[t];
        const float* pb = pooled + b * NPTS;
        for (int n = 0; n < NPTS; ++n)
            acc = fmaf(pb[n], w_cls[n * 40 + t], acc);
        out[b * 40 + t] = acc;
    }
}

extern "C" void kernel_launch(void* const* d_in, const int* in_sizes, int n_in,
                              void* d_out, int out_size, void* d_ws, size_t ws_size,
                              hipStream_t stream) {
    const float* x      = (const float*)d_in[0];  // [16,512,16,1]
    const float* w_fm1  = (const float*)d_in[1];  // [1,20]
    const float* w_mix1 = (const float*)d_in[2];  // [1,30]
    const float* w_fm2  = (const float*)d_in[3];  // [30,20]
    const float* w_mix2 = (const float*)d_in[4];  // [30,50]
    const float* m_last = (const float*)d_in[5];  // [16,50]
    const float* w_cls  = (const float*)d_in[6];  // [512,40]
    const float* b_cls  = (const float*)d_in[7];  // [40]
    float* out = (float*)d_out;                   // [16,40]

    float* ws     = (float*)d_ws;
    float* R      = ws;                 // 16*512*16 = 131072 floats
    float* sqr    = ws + 131072;        // 8192 floats
    float* pooled = ws + 131072 + 8192; // 8192 floats

    const int BN = 16 * NPTS;           // 8192 rows

    stage1_kernel<<<BN, 64, 0, stream>>>(x, w_fm1, R, sqr);
    stage2_kernel<<<BN, 64, 0, stream>>>(R, sqr, w_fm2, w_mix1, w_mix2, m_last, pooled);
    classify_kernel<<<16, 64, 0, stream>>>(pooled, w_cls, b_cls, out);
}

// Round 2
// 140.749 us; speedup vs baseline: 1.3600x; 1.3600x over previous
//
#include <hip/hip_runtime.h>
#include <math.h>

#define KNN  20
#define INFK 0xFFFFFFFFu

// ---- helpers ---------------------------------------------------------------

// wave-wide min of packed u32 keys (lexicographic (dist,idx) since dist>=0)
__device__ __forceinline__ unsigned wave_min_u32(unsigned k) {
    #pragma unroll
    for (int off = 32; off >= 1; off >>= 1) {
        unsigned o = (unsigned)__shfl_xor((int)k, off, 64);
        k = (o < k) ? o : k;
    }
    return k;
}

// branchless sorted insert (ascending) into 8-reg list via min/max pairs
__device__ __forceinline__ void insert8(unsigned (&cd)[8], unsigned key) {
    #pragma unroll
    for (int i = 0; i < 8; ++i) {
        const unsigned lo = (cd[i] < key) ? cd[i] : key;
        const unsigned hi = (cd[i] < key) ? key : cd[i];
        cd[i] = lo; key = hi;
    }
}

// exact ascending-d fma chain dot product of two 16-float rows
__device__ __forceinline__ float dot16(const float4& o0, const float4& o1,
                                       const float4& o2, const float4& o3,
                                       const float4& a0, const float4& a1,
                                       const float4& a2, const float4& a3) {
    float d = 0.f;
    d = fmaf(o0.x, a0.x, d); d = fmaf(o0.y, a0.y, d); d = fmaf(o0.z, a0.z, d); d = fmaf(o0.w, a0.w, d);
    d = fmaf(o1.x, a1.x, d); d = fmaf(o1.y, a1.y, d); d = fmaf(o1.z, a1.z, d); d = fmaf(o1.w, a1.w, d);
    d = fmaf(o2.x, a2.x, d); d = fmaf(o2.y, a2.y, d); d = fmaf(o2.z, a2.z, d); d = fmaf(o2.w, a2.w, d);
    d = fmaf(o3.x, a3.x, d); d = fmaf(o3.y, a3.y, d); d = fmaf(o3.z, a3.z, d); d = fmaf(o3.w, a3.w, d);
    return d;
}

// ---- prep: softmax(w_fm1) and Q[k][f] = sum_c softmax(w_fm2)[c][k]*w_mix1[c]*w_mix2[c][f]
__global__ __launch_bounds__(256)
void prep_kernel(const float* __restrict__ w_fm1, const float* __restrict__ w_fm2,
                 const float* __restrict__ w_mix1, const float* __restrict__ w_mix2,
                 float* __restrict__ wn1, float* __restrict__ Q) {
    __shared__ float wc2[30][21];
    __shared__ float wm1[30];
    const int tid = threadIdx.x;
    if (tid < 30) {
        float wr[KNN]; float mx = -__builtin_inff();
        #pragma unroll
        for (int k = 0; k < KNN; ++k) { wr[k] = w_fm2[tid * KNN + k]; mx = fmaxf(mx, wr[k]); }
        float s = 0.f;
        #pragma unroll
        for (int k = 0; k < KNN; ++k) { wr[k] = __expf(wr[k] - mx); s += wr[k]; }
        const float inv = 1.f / s;
        #pragma unroll
        for (int k = 0; k < KNN; ++k) wc2[tid][k] = wr[k] * inv;
        wm1[tid] = w_mix1[tid];
    }
    if (tid == 32) {
        float v[KNN]; float mx = -__builtin_inff();
        #pragma unroll
        for (int k = 0; k < KNN; ++k) { v[k] = w_fm1[k]; mx = fmaxf(mx, v[k]); }
        float s = 0.f;
        #pragma unroll
        for (int k = 0; k < KNN; ++k) { v[k] = __expf(v[k] - mx); s += v[k]; }
        const float inv = 1.f / s;
        #pragma unroll
        for (int k = 0; k < KNN; ++k) wn1[k] = v[k] * inv;
    }
    __syncthreads();
    for (int e = tid; e < KNN * 50; e += 256) {
        const int k = e / 50, f = e - k * 50;
        float acc = 0.f;
        #pragma unroll
        for (int c = 0; c < 30; ++c)
            acc = fmaf(wc2[c][k] * wm1[c], w_mix2[c * 50 + f], acc);
        Q[e] = acc;
    }
}

// ---- stage 1: KNN on raw 16-d points + wFM -> R[b,n,16], sqr[b,n]=||R||^2
__global__ __launch_bounds__(256)
void stage1_kernel(const float* __restrict__ x, const float* __restrict__ wn1,
                   float* __restrict__ R, float* __restrict__ sqr) {
    __shared__ unsigned sk[4 * 576];     // per-wave 64 x 9 (pad -> conflict-free)
    __shared__ unsigned nbrS[4 * KNN];
    __shared__ float    swn[KNN];
    const int tid = threadIdx.x;
    if (tid < KNN) swn[tid] = wn1[tid];
    __syncthreads();

    const int t = tid & 63, w = tid >> 6;
    const int row = blockIdx.x * 4 + w;
    const int b = row >> 9, n = row & 511;
    const float* xb = x + (size_t)b * 8192;

    const float4* xn4 = (const float4*)(xb + n * 16);
    const float4 o0 = xn4[0], o1 = xn4[1], o2 = xn4[2], o3 = xn4[3];
    const float sqn = dot16(o0, o1, o2, o3, o0, o1, o2, o3);

    unsigned cd[8];
    #pragma unroll
    for (int i = 0; i < 8; ++i) cd[i] = INFK;

    #pragma unroll
    for (int j = 0; j < 8; ++j) {
        const int m = j * 64 + t;
        const float4* xm4 = (const float4*)(xb + m * 16);
        const float4 a0 = xm4[0], a1 = xm4[1], a2 = xm4[2], a3 = xm4[3];
        const float dot = dot16(o0, o1, o2, o3, a0, a1, a2, a3);
        const float sqm = dot16(a0, a1, a2, a3, a0, a1, a2, a3);
        float vd = fmaxf(sqn + sqm - 2.f * dot, 0.f);   // exact 0 at m==n
        insert8(cd, (__float_as_uint(vd) & 0xFFFFFE00u) | (unsigned)m);
    }

    unsigned* skw = sk + w * 576;
    #pragma unroll
    for (int i = 1; i < 8; ++i) skw[t * 9 + i] = cd[i];

    unsigned cur = cd[0];
    int h = 0;
    #pragma unroll
    for (int r = 0; r < KNN; ++r) {
        const unsigned bk = wave_min_u32(cur);
        if (t == 0) nbrS[w * KNN + r] = bk & 511u;
        if (cur == bk) { ++h; cur = (h < 8) ? skw[t * 9 + h] : INFK; }
    }

    // gather 20 neighbor rows (320 floats) into 5 regs/lane
    float nrf[5];
    #pragma unroll
    for (int j = 0; j < 5; ++j) {
        const int e = j * 64 + t;
        nrf[j] = xb[nbrS[w * KNN + (e >> 4)] * 16 + (e & 15)];
    }
    // R[d] = sum_k swn[k]*NR[k][d] for d = t < 16 (bpermute pulls; only t<16 valid)
    float racc = 0.f;
    #pragma unroll
    for (int k = 0; k < KNN; ++k) {
        const float nr = __shfl(nrf[k >> 2], (k * 16 + t) & 63, 64);
        racc = fmaf(swn[k], nr, racc);
    }
    if (t < 16) R[(size_t)row * 16 + t] = racc;
    // sqr with the SAME ascending-d fma chain as stage-2's dot (diag -> exact 0)
    float s2 = 0.f;
    #pragma unroll
    for (int d = 0; d < 16; ++d) {
        const float rv = __int_as_float(__builtin_amdgcn_readlane(__float_as_int(racc), d));
        s2 = fmaf(rv, rv, s2);
    }
    if (t == 0) sqr[row] = s2;
}

// ---- stage 2: KNN on R + fused (wFM2 . mix2) via Q + manifold dist + pool
__global__ __launch_bounds__(256)
void stage2_kernel(const float* __restrict__ Rg, const float* __restrict__ sqr,
                   const float* __restrict__ Q, const float* __restrict__ m_last,
                   float* __restrict__ pooled) {
    __shared__ float    sQ[KNN * 50];
    __shared__ float    sM[16 * 50];
    __shared__ unsigned sk[4 * 576];
    __shared__ unsigned nbrS[4 * KNN];
    const int tid = threadIdx.x;
    for (int e = tid; e < KNN * 50; e += 256) sQ[e] = Q[e];
    for (int e = tid; e < 16 * 50; e += 256) sM[e] = m_last[e];
    __syncthreads();

    const int t = tid & 63, w = tid >> 6;
    const int row = blockIdx.x * 4 + w;
    const int b = row >> 9, n = row & 511;
    const float* Rb = Rg + (size_t)b * 8192;
    const float* sb = sqr + b * 512;

    const float4* rn4 = (const float4*)(Rb + n * 16);
    const float4 o0 = rn4[0], o1 = rn4[1], o2 = rn4[2], o3 = rn4[3];
    const float sqn = sb[n];

    unsigned cd[8];
    #pragma unroll
    for (int i = 0; i < 8; ++i) cd[i] = INFK;

    #pragma unroll
    for (int j = 0; j < 8; ++j) {
        const int m = j * 64 + t;
        const float4* rm4 = (const float4*)(Rb + m * 16);
        const float4 a0 = rm4[0], a1 = rm4[1], a2 = rm4[2], a3 = rm4[3];
        const float dot = dot16(o0, o1, o2, o3, a0, a1, a2, a3);
        float vd = fmaxf(sqn + sb[m] - 2.f * dot, 0.f);   // exact 0 at m==n
        insert8(cd, (__float_as_uint(vd) & 0xFFFFFE00u) | (unsigned)m);
    }

    unsigned* skw = sk + w * 576;
    #pragma unroll
    for (int i = 1; i < 8; ++i) skw[t * 9 + i] = cd[i];

    unsigned cur = cd[0];
    int h = 0;
    #pragma unroll
    for (int r = 0; r < KNN; ++r) {
        const unsigned bk = wave_min_u32(cur);
        if (t == 0) nbrS[w * KNN + r] = bk & 511u;
        if (cur == bk) { ++h; cur = (h < 8) ? skw[t * 9 + h] : INFK; }
    }

    float nrf[5];
    #pragma unroll
    for (int j = 0; j < 5; ++j) {
        const int e = j * 64 + t;
        nrf[j] = Rb[nbrS[w * KNN + (e >> 4)] * 16 + (e & 15)];
    }

    // lane f<50: v[d] = sum_k NR[k][d]*Q[k][f]; dist = sqrt(sum_d (v-m)^2 + 1e-8)
    const int f = (t < 50) ? t : 49;
    float q[KNN];
    #pragma unroll
    for (int k = 0; k < KNN; ++k) q[k] = sQ[k * 50 + f];
    float acc = 0.f;
    #pragma unroll
    for (int d = 0; d < 16; ++d) {
        float v = 0.f;
        #pragma unroll
        for (int k = 0; k < KNN; ++k) {
            const int e = k * 16 + d;
            const float nr = __int_as_float(
                __builtin_amdgcn_readlane(__float_as_int(nrf[e >> 6]), e & 63));
            v = fmaf(nr, q[k], v);
        }
        v -= sM[d * 50 + f];
        acc = fmaf(v, v, acc);
    }
    float dist50 = (t < 50) ? sqrtf(acc + 1e-8f) : 0.f;
    #pragma unroll
    for (int off = 32; off >= 1; off >>= 1) dist50 += __shfl_xor(dist50, off, 64);
    if (t == 0) pooled[row] = dist50 * (1.0f / 50.0f);
}

// ---- classifier ------------------------------------------------------------
__global__ __launch_bounds__(64)
void classify_kernel(const float* __restrict__ pooled, const float* __restrict__ w_cls,
                     const float* __restrict__ b_cls, float* __restrict__ out) {
    const int b = blockIdx.x, t = threadIdx.x;
    if (t < 40) {
        float acc = b_cls[t];
        const float* pb = pooled + b * 512;
        for (int n = 0; n < 512; ++n)
            acc = fmaf(pb[n], w_cls[n * 40 + t], acc);
        out[b * 40 + t] = acc;
    }
}

extern "C" void kernel_launch(void* const* d_in, const int* in_sizes, int n_in,
                              void* d_out, int out_size, void* d_ws, size_t ws_size,
                              hipStream_t stream) {
    const float* x      = (const float*)d_in[0];
    const float* w_fm1  = (const float*)d_in[1];
    const float* w_mix1 = (const float*)d_in[2];
    const float* w_fm2  = (const float*)d_in[3];
    const float* w_mix2 = (const float*)d_in[4];
    const float* m_last = (const float*)d_in[5];
    const float* w_cls  = (const float*)d_in[6];
    const float* b_cls  = (const float*)d_in[7];
    float* out = (float*)d_out;

    float* ws     = (float*)d_ws;
    float* R      = ws;                  // 131072
    float* sqrb   = ws + 131072;         // 8192
    float* pooled = ws + 139264;         // 8192
    float* wn1    = ws + 147456;         // 20
    float* Q      = ws + 147476;         // 1000

    prep_kernel<<<1, 256, 0, stream>>>(w_fm1, w_fm2, w_mix1, w_mix2, wn1, Q);
    stage1_kernel<<<2048, 256, 0, stream>>>(x, wn1, R, sqrb);
    stage2_kernel<<<2048, 256, 0, stream>>>(R, sqrb, Q, m_last, pooled);
    classify_kernel<<<16, 64, 0, stream>>>(pooled, w_cls, b_cls, out);
}